// Round 7
// baseline (343.639 us; speedup 1.0000x reference)
//
#include <hip/hip_runtime.h>
#include <math.h>

#define N_NODES 100000
#define N_EDGES 1600000
#define EPS_    1e-5f
#define PAD     64          // ELL row capacity; P(Poisson(16) > 64) ~ 1e-20
#define SCOL    48          // staged ELL columns; P(deg > 48) ~ 1e-12/node

#define NB_EDGE  6250       // E/256 exactly: one edge per thread
#define NB_LIN   391        // x2 waves (128 thr) = 782 chunks of 128 nodes
#define LIN_CHUNKS 782

// R15: ATTRIBUTION ROUND. R8-R14: every fused build variant sits at 125-139us;
// Phase A (1.6M atomic+scatter) and Phase B (lin) were always overlapped, so
// duration=max() hid which is the floor. De-fuse into 4 separately-profiled
// kernels, each in its best-known form:
//   edge_kernel  : Phase A alone  -> direct atomic+scatter floor measurement
//   lin_kernel   : float4 M=2 lin -> direct operand-delivery measurement
//   scale_kernel : prescale hb_g by dinv (known ~6us)
//   gather_final : R14 form (256-thr blocks, coalesced ELL->LDS stage)
// Branch for R16: edge~127 -> kill global atomics (full-line binning);
// lin>=100 -> MFMA lin + re-fuse.

// ---- bf16 helpers (raw ushort storage, RNE on pack) -----------------------
__device__ __forceinline__ float bf2f(unsigned short u) {
    union { unsigned int i; float f; } v; v.i = (unsigned int)u << 16; return v.f;
}
__device__ __forceinline__ unsigned short f2bf(float f) {
    union { float f; unsigned int i; } v; v.f = f;
    unsigned int b = v.i + 0x7FFFu + ((v.i >> 16) & 1u);   // round-to-nearest-even
    return (unsigned short)(b >> 16);
}

// ---------------------------------------------------------------------------
// Kernel 1: edge scatter ONLY. One edge per thread.
// ---------------------------------------------------------------------------
__global__ void edge_kernel(const int* __restrict__ src,
                            const int* __restrict__ dst,
                            int* __restrict__ cnt,
                            int* __restrict__ ell)
{
    const int gtid = blockIdx.x * 256 + threadIdx.x;   // grid covers E exactly
    const int d    = dst[gtid];
    const int s    = src[gtid];
    const int pos  = atomicAdd(&cnt[d], 1);
    if (pos < PAD) ell[d * PAD + pos] = s;
}

// ---------------------------------------------------------------------------
// Kernel 2: lin ONLY (R13 form). lane = node, 2 nodes per lane (A/B), acc in
// VGPRs, Wg read as float4 wave-uniform loads. hb_g stored UNSCALED.
// ---------------------------------------------------------------------------
__global__ void lin_kernel(const float* __restrict__ x,
                           const float* __restrict__ W1,
                           const float* __restrict__ b1,
                           const float* __restrict__ Wg,
                           unsigned short* __restrict__ hb_g)
{
    const int tl    = threadIdx.x;            // 128 threads = 2 waves
    const int chunk = blockIdx.x * 2 + (tl >> 6);
    if (chunk >= LIN_CHUNKS) return;

    const int lane = tl & 63;
    const int nA   = chunk * 128 + lane;
    const int nB   = nA + 64;
    const bool actA = (nA < N_NODES);
    const bool actB = (nB < N_NODES);

    float xA0 = 0.f, xA1 = 0.f, xA2 = 0.f, xB0 = 0.f, xB1 = 0.f, xB2 = 0.f;
    if (actA) { xA0 = x[nA * 3]; xA1 = x[nA * 3 + 1]; xA2 = x[nA * 3 + 2]; }
    if (actB) { xB0 = x[nB * 3]; xB1 = x[nB * 3 + 1]; xB2 = x[nB * 3 + 2]; }

    float accA[64], accB[64];
#pragma unroll
    for (int c = 0; c < 64; ++c) { accA[c] = 0.f; accB[c] = 0.f; }

    for (int k = 0; k < 64; ++k) {
        const float w0 = W1[k];                // wave-uniform
        const float w1 = W1[64 + k];
        const float w2 = W1[128 + k];
        const float bb = b1[k];
        float hA = fmaf(xA0, w0, fmaf(xA1, w1, fmaf(xA2, w2, bb)));
        float hB = fmaf(xB0, w0, fmaf(xB1, w1, fmaf(xB2, w2, bb)));
        hA = fmaxf(hA, 0.f);
        hB = fmaxf(hB, 0.f);

        const float4* __restrict__ row4 = (const float4*)(Wg + k * 64);
#pragma unroll
        for (int c4 = 0; c4 < 16; ++c4) {
            const float4 wv = row4[c4];
            accA[4 * c4 + 0] = fmaf(hA, wv.x, accA[4 * c4 + 0]);
            accA[4 * c4 + 1] = fmaf(hA, wv.y, accA[4 * c4 + 1]);
            accA[4 * c4 + 2] = fmaf(hA, wv.z, accA[4 * c4 + 2]);
            accA[4 * c4 + 3] = fmaf(hA, wv.w, accA[4 * c4 + 3]);
            accB[4 * c4 + 0] = fmaf(hB, wv.x, accB[4 * c4 + 0]);
            accB[4 * c4 + 1] = fmaf(hB, wv.y, accB[4 * c4 + 1]);
            accB[4 * c4 + 2] = fmaf(hB, wv.z, accB[4 * c4 + 2]);
            accB[4 * c4 + 3] = fmaf(hB, wv.w, accB[4 * c4 + 3]);
        }
    }

    if (actA) {
        unsigned int o[32];
#pragma unroll
        for (int c = 0; c < 32; ++c)
            o[c] = (unsigned int)f2bf(accA[2 * c])
                 | ((unsigned int)f2bf(accA[2 * c + 1]) << 16);
        uint4* __restrict__ dp = (uint4*)(hb_g + (size_t)nA * 64);
#pragma unroll
        for (int q = 0; q < 8; ++q)
            dp[q] = make_uint4(o[4 * q], o[4 * q + 1], o[4 * q + 2], o[4 * q + 3]);
    }
    if (actB) {
        unsigned int o[32];
#pragma unroll
        for (int c = 0; c < 32; ++c)
            o[c] = (unsigned int)f2bf(accB[2 * c])
                 | ((unsigned int)f2bf(accB[2 * c + 1]) << 16);
        uint4* __restrict__ dp = (uint4*)(hb_g + (size_t)nB * 64);
#pragma unroll
        for (int q = 0; q < 8; ++q)
            dp[q] = make_uint4(o[4 * q], o[4 * q + 1], o[4 * q + 2], o[4 * q + 3]);
    }
}

// ---------------------------------------------------------------------------
// Kernel 3: hb_g[n][c] *= rsqrt(cnt[n]+1)  (in place, dword grain, ~6 us)
// ---------------------------------------------------------------------------
__global__ void scale_kernel(const int* __restrict__ cnt,
                             unsigned int* __restrict__ g2)
{
    const int t = blockIdx.x * blockDim.x + threadIdx.x;
    if (t >= N_NODES * 32) return;
    const int node = t >> 5;
    const float di = rsqrtf((float)(cnt[node] + 1));
    const unsigned int v = g2[t];
    const float lo = bf2f((unsigned short)(v & 0xFFFFu)) * di;
    const float hi = bf2f((unsigned short)(v >> 16)) * di;
    g2[t] = (unsigned int)f2bf(lo) | ((unsigned int)f2bf(hi) << 16);
}

// ---------------------------------------------------------------------------
// Kernel 4: gather + epilogue (R14 form). 256 threads = 4 waves, 64 nodes per
// block. Branch-free coalesced stage of 48 ELL cols + cnt into LDS, then
// wave-per-node gather (prescaled hb_g: no dinv loads).
// ---------------------------------------------------------------------------
__global__ void gather_final_kernel(const unsigned short* __restrict__ hb_g,
                                    const int* __restrict__ cnt,
                                    const int* __restrict__ ell,
                                    const float* __restrict__ x,
                                    const float* __restrict__ W1,
                                    const float* __restrict__ b1,
                                    const float* __restrict__ bg,
                                    const float* __restrict__ gamma,
                                    const float* __restrict__ beta,
                                    float* __restrict__ out)
{
    __shared__ int sell[64 * SCOL];       // 12 KB
    __shared__ int lcnt[64];
    const int tl = threadIdx.x;           // 256 threads = 4 waves
    const int b  = blockIdx.x;
    const int nb = b * 64;

    // ---- stage: cnt -> lcnt, 48 ELL cols -> sell (3 int4 per thread) -----
    if (tl < 64) {
        const int n = nb + tl;
        lcnt[tl] = (n < N_NODES) ? cnt[n] : 0;
    }
    {
        const int r = tl >> 2;            // row 0..63
        const int q = tl & 3;             // quad 0..3
        const int nr = nb + r;
        if (nr < N_NODES) {
            const int4* __restrict__ grow = (const int4*)(ell + (size_t)nr * PAD);
            int4* __restrict__ srow = (int4*)(sell + r * SCOL);
            srow[q]     = grow[q];        // cols  0..15
            srow[q + 4] = grow[q + 4];    // cols 16..31
            srow[q + 8] = grow[q + 8];    // cols 32..47
        }
    }
    __syncthreads();

    const int lane = tl & 63;
    const int w    = tl >> 6;
    const float w0 = W1[lane], w1 = W1[64 + lane], w2 = W1[128 + lane];
    const float bb1 = b1[lane];
    const float bgl = bg[lane];
    const float g0 = gamma[lane], g1 = gamma[64 + lane];
    const float be0 = beta[lane], be1 = beta[64 + lane];

    for (int nl = w; nl < 64; nl += 4) {
        const int n = nb + nl;
        if (n >= N_NODES) break;          // only the last block's tail

        const int c    = lcnt[nl];
        const float di = rsqrtf((float)(c + 1));
        const int deg  = (c < PAD) ? c : PAD;
        const int dstg = (deg < SCOL) ? deg : SCOL;
        const int* row = sell + nl * SCOL;

        const float xx0 = x[n * 3], xx1 = x[n * 3 + 1], xx2 = x[n * 3 + 2];
        float acc = bf2f(hb_g[(size_t)n * 64 + lane]);       // self (prescaled)

        int j = 0;
        for (; j + 8 <= dstg; j += 8) {                      // 8 gathers in flight
            const int s0 = row[j + 0], s1 = row[j + 1], s2 = row[j + 2], s3 = row[j + 3];
            const int s4 = row[j + 4], s5 = row[j + 5], s6 = row[j + 6], s7 = row[j + 7];
            const float a0 = bf2f(hb_g[(size_t)s0 * 64 + lane]);
            const float a1 = bf2f(hb_g[(size_t)s1 * 64 + lane]);
            const float a2 = bf2f(hb_g[(size_t)s2 * 64 + lane]);
            const float a3 = bf2f(hb_g[(size_t)s3 * 64 + lane]);
            const float a4 = bf2f(hb_g[(size_t)s4 * 64 + lane]);
            const float a5 = bf2f(hb_g[(size_t)s5 * 64 + lane]);
            const float a6 = bf2f(hb_g[(size_t)s6 * 64 + lane]);
            const float a7 = bf2f(hb_g[(size_t)s7 * 64 + lane]);
            acc += ((a0 + a1) + (a2 + a3)) + ((a4 + a5) + (a6 + a7));
        }
        if (j + 4 <= dstg) {
            const int s0 = row[j + 0], s1 = row[j + 1], s2 = row[j + 2], s3 = row[j + 3];
            acc += (bf2f(hb_g[(size_t)s0 * 64 + lane]) + bf2f(hb_g[(size_t)s1 * 64 + lane]))
                 + (bf2f(hb_g[(size_t)s2 * 64 + lane]) + bf2f(hb_g[(size_t)s3 * 64 + lane]));
            j += 4;
        }
        for (; j < dstg; ++j) acc += bf2f(hb_g[(size_t)row[j] * 64 + lane]);
        // astronomically-rare tail (deg > 48): read global ELL row directly
        for (; j < deg; ++j)
            acc += bf2f(hb_g[(size_t)ell[(size_t)n * PAD + j] * 64 + lane]);

        float h  = fmaxf(fmaf(xx0, w0, fmaf(xx1, w1, fmaf(xx2, w2, bb1))), 0.f);
        float h2 = fmaxf(fmaf(di, acc, bgl), 0.f);

        float sum = h + h2;
#pragma unroll
        for (int o = 32; o > 0; o >>= 1) sum += __shfl_xor(sum, o, 64);
        const float mu = sum * (1.0f / 128.0f);

        const float dA = h  - mu;
        const float dB = h2 - mu;
        float vs = dA * dA + dB * dB;
#pragma unroll
        for (int o = 32; o > 0; o >>= 1) vs += __shfl_xor(vs, o, 64);
        const float rr = rsqrtf(vs * (1.0f / 128.0f) + EPS_);

        out[(size_t)n * 128 + lane]      = dA * rr * g0 + be0;
        out[(size_t)n * 128 + 64 + lane] = dB * rr * g1 + be1;
    }
}

// ---------------------------------------------------------------------------
extern "C" void kernel_launch(void* const* d_in, const int* in_sizes, int n_in,
                              void* d_out, int out_size, void* d_ws, size_t ws_size,
                              hipStream_t stream)
{
    const float* x     = (const float*)d_in[0];
    const int*   edge  = (const int*)  d_in[1];   // [2, E]: row0 = src, row1 = dst
    const float* W1    = (const float*)d_in[2];
    const float* b1    = (const float*)d_in[3];
    const float* Wg    = (const float*)d_in[4];
    const float* bg    = (const float*)d_in[5];
    const float* gamma = (const float*)d_in[6];
    const float* beta  = (const float*)d_in[7];
    float*       out   = (float*)d_out;

    // Workspace (~38.8 MB): hb_g | ell | cnt  (16B-aligned)
    char*  ws  = (char*)d_ws;
    size_t p   = 0;
    unsigned short* hb_g = (unsigned short*)(ws + p); p += (size_t)N_NODES * 64 * sizeof(unsigned short);
    int*            ell  = (int*)           (ws + p); p += (size_t)N_NODES * PAD * sizeof(int);
    int*            cnt  = (int*)           (ws + p);

    const int* src = edge;
    const int* dst = edge + N_EDGES;

    hipMemsetAsync(cnt, 0, (size_t)N_NODES * sizeof(int), stream);

    edge_kernel<<<NB_EDGE, 256, 0, stream>>>(src, dst, cnt, ell);
    lin_kernel <<<NB_LIN,  128, 0, stream>>>(x, W1, b1, Wg, hb_g);
    scale_kernel<<<(N_NODES * 32 + 255) / 256, 256, 0, stream>>>(cnt, (unsigned int*)hb_g);
    gather_final_kernel<<<(N_NODES + 63) / 64, 256, 0, stream>>>(hb_g, cnt, ell,
                                                                 x, W1, b1,
                                                                 bg, gamma, beta, out);
}

// Round 8
// 293.258 us; speedup vs baseline: 1.1718x; 1.1718x over previous
//
#include <hip/hip_runtime.h>
#include <math.h>

#define N_NODES 100000
#define N_EDGES 1600000
#define EPS_    1e-5f
#define PAD     64          // ELL row capacity; P(Poisson(16) > 64) ~ 1e-20
#define SCOL    48          // staged ELL columns; P(deg > 48) ~ 1e-12/node

// R16: clean XCD-partition A/B on the ISOLATED edge kernel.
// R15 measured Phase A alone: 135us, VALU 0.3%, WRITE 96MB (= 1.6M x 60B:
// every 4B ELL store -> one partial-line writeback; lines dirtied in up to 8
// non-coherent XCD L2s). R9's partition null was MASKED by the fused lin's
// ~120us floor. Here: 8 sibling blocks per 2048-edge chunk, sibling p owns
// dst in [p*12500,(p+1)*12500) -> each ELL/cnt line assembled in ONE L2,
// written back once, full. lin/scale/gather unchanged from R15 (single var).
#define NCHUNK_E 782        // ceil(E/2048)
#define EPB_E    2048
#define NB_EDGE  (NCHUNK_E * 8)
#define PART_SZ  12500      // N_NODES / 8

#define NB_LIN   391        // x2 waves (128 thr) = 782 chunks of 128 nodes
#define LIN_CHUNKS 782

// ---- bf16 helpers (raw ushort storage, RNE on pack) -----------------------
__device__ __forceinline__ float bf2f(unsigned short u) {
    union { unsigned int i; float f; } v; v.i = (unsigned int)u << 16; return v.f;
}
__device__ __forceinline__ unsigned short f2bf(float f) {
    union { float f; unsigned int i; } v; v.f = f;
    unsigned int b = v.i + 0x7FFFu + ((v.i >> 16) & 1u);   // round-to-nearest-even
    return (unsigned short)(b >> 16);
}

// ---------------------------------------------------------------------------
// Kernel 1: edge scatter, XCD-partitioned. Block (chunk, part) bulk-reads its
// 2048-edge chunk (int4, L2/L3-served for siblings) and claims only edges
// whose dst lies in its partition.
// ---------------------------------------------------------------------------
__global__ void edge_kernel(const int* __restrict__ src,
                            const int* __restrict__ dst,
                            int* __restrict__ cnt,
                            int* __restrict__ ell)
{
    const int part  = blockIdx.x & 7;          // aligns with round-robin XCD dispatch
    const int chunk = blockIdx.x >> 3;
    const int lo    = part * PART_SZ;
    const int hi    = lo + PART_SZ;

    const int ebase = chunk * EPB_E + threadIdx.x * 8;
    int dv[8], sv[8];
    if (ebase + 8 <= N_EDGES) {
        const int4 d0 = *(const int4*)(dst + ebase);
        const int4 d1 = *(const int4*)(dst + ebase + 4);
        const int4 s0 = *(const int4*)(src + ebase);
        const int4 s1 = *(const int4*)(src + ebase + 4);
        dv[0] = d0.x; dv[1] = d0.y; dv[2] = d0.z; dv[3] = d0.w;
        dv[4] = d1.x; dv[5] = d1.y; dv[6] = d1.z; dv[7] = d1.w;
        sv[0] = s0.x; sv[1] = s0.y; sv[2] = s0.z; sv[3] = s0.w;
        sv[4] = s1.x; sv[5] = s1.y; sv[6] = s1.z; sv[7] = s1.w;
    } else {
#pragma unroll
        for (int j = 0; j < 8; ++j) {
            const int e = ebase + j;
            if (e < N_EDGES) { dv[j] = dst[e]; sv[j] = src[e]; }
            else             { dv[j] = -1;     sv[j] = 0;      }
        }
    }

#pragma unroll
    for (int j = 0; j < 8; ++j) {
        if (dv[j] >= lo && dv[j] < hi) {
            const int pos = atomicAdd(&cnt[dv[j]], 1);
            if (pos < PAD) ell[dv[j] * PAD + pos] = sv[j];
        }
    }
}

// ---------------------------------------------------------------------------
// Kernel 2: lin (R13 form, unchanged). lane = node, 2 nodes per lane, acc in
// VGPRs, Wg read as float4 wave-uniform loads. hb_g stored UNSCALED.
// ---------------------------------------------------------------------------
__global__ void lin_kernel(const float* __restrict__ x,
                           const float* __restrict__ W1,
                           const float* __restrict__ b1,
                           const float* __restrict__ Wg,
                           unsigned short* __restrict__ hb_g)
{
    const int tl    = threadIdx.x;            // 128 threads = 2 waves
    const int chunk = blockIdx.x * 2 + (tl >> 6);
    if (chunk >= LIN_CHUNKS) return;

    const int lane = tl & 63;
    const int nA   = chunk * 128 + lane;
    const int nB   = nA + 64;
    const bool actA = (nA < N_NODES);
    const bool actB = (nB < N_NODES);

    float xA0 = 0.f, xA1 = 0.f, xA2 = 0.f, xB0 = 0.f, xB1 = 0.f, xB2 = 0.f;
    if (actA) { xA0 = x[nA * 3]; xA1 = x[nA * 3 + 1]; xA2 = x[nA * 3 + 2]; }
    if (actB) { xB0 = x[nB * 3]; xB1 = x[nB * 3 + 1]; xB2 = x[nB * 3 + 2]; }

    float accA[64], accB[64];
#pragma unroll
    for (int c = 0; c < 64; ++c) { accA[c] = 0.f; accB[c] = 0.f; }

    for (int k = 0; k < 64; ++k) {
        const float w0 = W1[k];                // wave-uniform
        const float w1 = W1[64 + k];
        const float w2 = W1[128 + k];
        const float bb = b1[k];
        float hA = fmaf(xA0, w0, fmaf(xA1, w1, fmaf(xA2, w2, bb)));
        float hB = fmaf(xB0, w0, fmaf(xB1, w1, fmaf(xB2, w2, bb)));
        hA = fmaxf(hA, 0.f);
        hB = fmaxf(hB, 0.f);

        const float4* __restrict__ row4 = (const float4*)(Wg + k * 64);
#pragma unroll
        for (int c4 = 0; c4 < 16; ++c4) {
            const float4 wv = row4[c4];
            accA[4 * c4 + 0] = fmaf(hA, wv.x, accA[4 * c4 + 0]);
            accA[4 * c4 + 1] = fmaf(hA, wv.y, accA[4 * c4 + 1]);
            accA[4 * c4 + 2] = fmaf(hA, wv.z, accA[4 * c4 + 2]);
            accA[4 * c4 + 3] = fmaf(hA, wv.w, accA[4 * c4 + 3]);
            accB[4 * c4 + 0] = fmaf(hB, wv.x, accB[4 * c4 + 0]);
            accB[4 * c4 + 1] = fmaf(hB, wv.y, accB[4 * c4 + 1]);
            accB[4 * c4 + 2] = fmaf(hB, wv.z, accB[4 * c4 + 2]);
            accB[4 * c4 + 3] = fmaf(hB, wv.w, accB[4 * c4 + 3]);
        }
    }

    if (actA) {
        unsigned int o[32];
#pragma unroll
        for (int c = 0; c < 32; ++c)
            o[c] = (unsigned int)f2bf(accA[2 * c])
                 | ((unsigned int)f2bf(accA[2 * c + 1]) << 16);
        uint4* __restrict__ dp = (uint4*)(hb_g + (size_t)nA * 64);
#pragma unroll
        for (int q = 0; q < 8; ++q)
            dp[q] = make_uint4(o[4 * q], o[4 * q + 1], o[4 * q + 2], o[4 * q + 3]);
    }
    if (actB) {
        unsigned int o[32];
#pragma unroll
        for (int c = 0; c < 32; ++c)
            o[c] = (unsigned int)f2bf(accB[2 * c])
                 | ((unsigned int)f2bf(accB[2 * c + 1]) << 16);
        uint4* __restrict__ dp = (uint4*)(hb_g + (size_t)nB * 64);
#pragma unroll
        for (int q = 0; q < 8; ++q)
            dp[q] = make_uint4(o[4 * q], o[4 * q + 1], o[4 * q + 2], o[4 * q + 3]);
    }
}

// ---------------------------------------------------------------------------
// Kernel 3: hb_g[n][c] *= rsqrt(cnt[n]+1)  (in place, dword grain, ~6 us)
// ---------------------------------------------------------------------------
__global__ void scale_kernel(const int* __restrict__ cnt,
                             unsigned int* __restrict__ g2)
{
    const int t = blockIdx.x * blockDim.x + threadIdx.x;
    if (t >= N_NODES * 32) return;
    const int node = t >> 5;
    const float di = rsqrtf((float)(cnt[node] + 1));
    const unsigned int v = g2[t];
    const float lo = bf2f((unsigned short)(v & 0xFFFFu)) * di;
    const float hi = bf2f((unsigned short)(v >> 16)) * di;
    g2[t] = (unsigned int)f2bf(lo) | ((unsigned int)f2bf(hi) << 16);
}

// ---------------------------------------------------------------------------
// Kernel 4: gather + epilogue (R14/R15 form, unchanged).
// ---------------------------------------------------------------------------
__global__ void gather_final_kernel(const unsigned short* __restrict__ hb_g,
                                    const int* __restrict__ cnt,
                                    const int* __restrict__ ell,
                                    const float* __restrict__ x,
                                    const float* __restrict__ W1,
                                    const float* __restrict__ b1,
                                    const float* __restrict__ bg,
                                    const float* __restrict__ gamma,
                                    const float* __restrict__ beta,
                                    float* __restrict__ out)
{
    __shared__ int sell[64 * SCOL];       // 12 KB
    __shared__ int lcnt[64];
    const int tl = threadIdx.x;           // 256 threads = 4 waves
    const int b  = blockIdx.x;
    const int nb = b * 64;

    if (tl < 64) {
        const int n = nb + tl;
        lcnt[tl] = (n < N_NODES) ? cnt[n] : 0;
    }
    {
        const int r = tl >> 2;            // row 0..63
        const int q = tl & 3;             // quad 0..3
        const int nr = nb + r;
        if (nr < N_NODES) {
            const int4* __restrict__ grow = (const int4*)(ell + (size_t)nr * PAD);
            int4* __restrict__ srow = (int4*)(sell + r * SCOL);
            srow[q]     = grow[q];        // cols  0..15
            srow[q + 4] = grow[q + 4];    // cols 16..31
            srow[q + 8] = grow[q + 8];    // cols 32..47
        }
    }
    __syncthreads();

    const int lane = tl & 63;
    const int w    = tl >> 6;
    const float w0 = W1[lane], w1 = W1[64 + lane], w2 = W1[128 + lane];
    const float bb1 = b1[lane];
    const float bgl = bg[lane];
    const float g0 = gamma[lane], g1 = gamma[64 + lane];
    const float be0 = beta[lane], be1 = beta[64 + lane];

    for (int nl = w; nl < 64; nl += 4) {
        const int n = nb + nl;
        if (n >= N_NODES) break;          // only the last block's tail

        const int c    = lcnt[nl];
        const float di = rsqrtf((float)(c + 1));
        const int deg  = (c < PAD) ? c : PAD;
        const int dstg = (deg < SCOL) ? deg : SCOL;
        const int* row = sell + nl * SCOL;

        const float xx0 = x[n * 3], xx1 = x[n * 3 + 1], xx2 = x[n * 3 + 2];
        float acc = bf2f(hb_g[(size_t)n * 64 + lane]);       // self (prescaled)

        int j = 0;
        for (; j + 8 <= dstg; j += 8) {                      // 8 gathers in flight
            const int s0 = row[j + 0], s1 = row[j + 1], s2 = row[j + 2], s3 = row[j + 3];
            const int s4 = row[j + 4], s5 = row[j + 5], s6 = row[j + 6], s7 = row[j + 7];
            const float a0 = bf2f(hb_g[(size_t)s0 * 64 + lane]);
            const float a1 = bf2f(hb_g[(size_t)s1 * 64 + lane]);
            const float a2 = bf2f(hb_g[(size_t)s2 * 64 + lane]);
            const float a3 = bf2f(hb_g[(size_t)s3 * 64 + lane]);
            const float a4 = bf2f(hb_g[(size_t)s4 * 64 + lane]);
            const float a5 = bf2f(hb_g[(size_t)s5 * 64 + lane]);
            const float a6 = bf2f(hb_g[(size_t)s6 * 64 + lane]);
            const float a7 = bf2f(hb_g[(size_t)s7 * 64 + lane]);
            acc += ((a0 + a1) + (a2 + a3)) + ((a4 + a5) + (a6 + a7));
        }
        if (j + 4 <= dstg) {
            const int s0 = row[j + 0], s1 = row[j + 1], s2 = row[j + 2], s3 = row[j + 3];
            acc += (bf2f(hb_g[(size_t)s0 * 64 + lane]) + bf2f(hb_g[(size_t)s1 * 64 + lane]))
                 + (bf2f(hb_g[(size_t)s2 * 64 + lane]) + bf2f(hb_g[(size_t)s3 * 64 + lane]));
            j += 4;
        }
        for (; j < dstg; ++j) acc += bf2f(hb_g[(size_t)row[j] * 64 + lane]);
        // astronomically-rare tail (deg > 48): read global ELL row directly
        for (; j < deg; ++j)
            acc += bf2f(hb_g[(size_t)ell[(size_t)n * PAD + j] * 64 + lane]);

        float h  = fmaxf(fmaf(xx0, w0, fmaf(xx1, w1, fmaf(xx2, w2, bb1))), 0.f);
        float h2 = fmaxf(fmaf(di, acc, bgl), 0.f);

        float sum = h + h2;
#pragma unroll
        for (int o = 32; o > 0; o >>= 1) sum += __shfl_xor(sum, o, 64);
        const float mu = sum * (1.0f / 128.0f);

        const float dA = h  - mu;
        const float dB = h2 - mu;
        float vs = dA * dA + dB * dB;
#pragma unroll
        for (int o = 32; o > 0; o >>= 1) vs += __shfl_xor(vs, o, 64);
        const float rr = rsqrtf(vs * (1.0f / 128.0f) + EPS_);

        out[(size_t)n * 128 + lane]      = dA * rr * g0 + be0;
        out[(size_t)n * 128 + 64 + lane] = dB * rr * g1 + be1;
    }
}

// ---------------------------------------------------------------------------
extern "C" void kernel_launch(void* const* d_in, const int* in_sizes, int n_in,
                              void* d_out, int out_size, void* d_ws, size_t ws_size,
                              hipStream_t stream)
{
    const float* x     = (const float*)d_in[0];
    const int*   edge  = (const int*)  d_in[1];   // [2, E]: row0 = src, row1 = dst
    const float* W1    = (const float*)d_in[2];
    const float* b1    = (const float*)d_in[3];
    const float* Wg    = (const float*)d_in[4];
    const float* bg    = (const float*)d_in[5];
    const float* gamma = (const float*)d_in[6];
    const float* beta  = (const float*)d_in[7];
    float*       out   = (float*)d_out;

    // Workspace (~38.8 MB): hb_g | ell | cnt  (16B-aligned)
    char*  ws  = (char*)d_ws;
    size_t p   = 0;
    unsigned short* hb_g = (unsigned short*)(ws + p); p += (size_t)N_NODES * 64 * sizeof(unsigned short);
    int*            ell  = (int*)           (ws + p); p += (size_t)N_NODES * PAD * sizeof(int);
    int*            cnt  = (int*)           (ws + p);

    const int* src = edge;
    const int* dst = edge + N_EDGES;

    hipMemsetAsync(cnt, 0, (size_t)N_NODES * sizeof(int), stream);

    edge_kernel<<<NB_EDGE, 256, 0, stream>>>(src, dst, cnt, ell);
    lin_kernel <<<NB_LIN,  128, 0, stream>>>(x, W1, b1, Wg, hb_g);
    scale_kernel<<<(N_NODES * 32 + 255) / 256, 256, 0, stream>>>(cnt, (unsigned int*)hb_g);
    gather_final_kernel<<<(N_NODES + 63) / 64, 256, 0, stream>>>(hb_g, cnt, ell,
                                                                 x, W1, b1,
                                                                 bg, gamma, beta, out);
}

// Round 9
// 249.030 us; speedup vs baseline: 1.3799x; 1.1776x over previous
//
#include <hip/hip_runtime.h>
#include <math.h>

#define N_NODES 100000
#define N_EDGES 1600000
#define EPS_    1e-5f
#define PAD     64          // ELL row capacity; P(Poisson(16) > 64) ~ 1e-20
#define SCOL    48          // staged ELL columns; P(deg > 48) ~ 1e-12/node

// R17: fix lin's SCRATCH-DEMOTED accumulator. R16 isolated lin at 80us with
// VGPR_Count=64 -- accA[64]+accB[64] (128 floats) cannot live in 64 VGPRs:
// the arrays were in scratch (L2-absorbed, invisible in FETCH/WRITE; VALU 18%,
// occ 7.3%). Same pathology explains R10/R11 build_lin (VGPR=40, acc[64]).
// Fix per guide rule #20: accumulator as 4 named ext_vector_type(16) vars,
// all element accesses compile-time constant. One node/lane, 1563 waves.
// edge (R16 XCD-partitioned -- it left the top-5), scale, gather unchanged.

#define NCHUNK_E 782        // ceil(E/2048)
#define EPB_E    2048
#define NB_EDGE  (NCHUNK_E * 8)
#define PART_SZ  12500      // N_NODES / 8

#define LIN_WAVES 1563      // ceil(N/64): one wave = 64 nodes, lane = node
#define NB_LIN    391       // x4 waves (256 thr) = 1564 waves

typedef float v16f __attribute__((ext_vector_type(16)));

// ---- bf16 helpers (raw ushort storage, RNE on pack) -----------------------
__device__ __forceinline__ float bf2f(unsigned short u) {
    union { unsigned int i; float f; } v; v.i = (unsigned int)u << 16; return v.f;
}
__device__ __forceinline__ unsigned short f2bf(float f) {
    union { float f; unsigned int i; } v; v.f = f;
    unsigned int b = v.i + 0x7FFFu + ((v.i >> 16) & 1u);   // round-to-nearest-even
    return (unsigned short)(b >> 16);
}
__device__ __forceinline__ unsigned int pk2(float lo, float hi) {
    return (unsigned int)f2bf(lo) | ((unsigned int)f2bf(hi) << 16);
}

// ---------------------------------------------------------------------------
// Kernel 1: edge scatter, XCD-partitioned (R16 form, unchanged).
// ---------------------------------------------------------------------------
__global__ void edge_kernel(const int* __restrict__ src,
                            const int* __restrict__ dst,
                            int* __restrict__ cnt,
                            int* __restrict__ ell)
{
    const int part  = blockIdx.x & 7;          // aligns with round-robin XCD dispatch
    const int chunk = blockIdx.x >> 3;
    const int lo    = part * PART_SZ;
    const int hi    = lo + PART_SZ;

    const int ebase = chunk * EPB_E + threadIdx.x * 8;
    int dv[8], sv[8];
    if (ebase + 8 <= N_EDGES) {
        const int4 d0 = *(const int4*)(dst + ebase);
        const int4 d1 = *(const int4*)(dst + ebase + 4);
        const int4 s0 = *(const int4*)(src + ebase);
        const int4 s1 = *(const int4*)(src + ebase + 4);
        dv[0] = d0.x; dv[1] = d0.y; dv[2] = d0.z; dv[3] = d0.w;
        dv[4] = d1.x; dv[5] = d1.y; dv[6] = d1.z; dv[7] = d1.w;
        sv[0] = s0.x; sv[1] = s0.y; sv[2] = s0.z; sv[3] = s0.w;
        sv[4] = s1.x; sv[5] = s1.y; sv[6] = s1.z; sv[7] = s1.w;
    } else {
#pragma unroll
        for (int j = 0; j < 8; ++j) {
            const int e = ebase + j;
            if (e < N_EDGES) { dv[j] = dst[e]; sv[j] = src[e]; }
            else             { dv[j] = -1;     sv[j] = 0;      }
        }
    }

#pragma unroll
    for (int j = 0; j < 8; ++j) {
        if (dv[j] >= lo && dv[j] < hi) {
            const int pos = atomicAdd(&cnt[dv[j]], 1);
            if (pos < PAD) ell[dv[j] * PAD + pos] = sv[j];
        }
    }
}

// ---------------------------------------------------------------------------
// Kernel 2: lin, register-resident accumulator. lane = node; acc = 4 named
// v16f (static element access only). W1/b1/Wg reads are wave-uniform ->
// scalar cache. hb_g stored UNSCALED (dinv folded by scale_kernel).
// ---------------------------------------------------------------------------
#define FMA16(A, wv0, wv1, wv2, wv3)                                          \
    do {                                                                      \
        A[0]  = fmaf(hk, wv0.x, A[0]);  A[1]  = fmaf(hk, wv0.y, A[1]);        \
        A[2]  = fmaf(hk, wv0.z, A[2]);  A[3]  = fmaf(hk, wv0.w, A[3]);        \
        A[4]  = fmaf(hk, wv1.x, A[4]);  A[5]  = fmaf(hk, wv1.y, A[5]);        \
        A[6]  = fmaf(hk, wv1.z, A[6]);  A[7]  = fmaf(hk, wv1.w, A[7]);        \
        A[8]  = fmaf(hk, wv2.x, A[8]);  A[9]  = fmaf(hk, wv2.y, A[9]);        \
        A[10] = fmaf(hk, wv2.z, A[10]); A[11] = fmaf(hk, wv2.w, A[11]);       \
        A[12] = fmaf(hk, wv3.x, A[12]); A[13] = fmaf(hk, wv3.y, A[13]);       \
        A[14] = fmaf(hk, wv3.z, A[14]); A[15] = fmaf(hk, wv3.w, A[15]);       \
    } while (0)

__global__ void lin_kernel(const float* __restrict__ x,
                           const float* __restrict__ W1,
                           const float* __restrict__ b1,
                           const float* __restrict__ Wg,
                           unsigned short* __restrict__ hb_g)
{
    const int tl   = threadIdx.x;                 // 256 threads = 4 waves
    const int wave = blockIdx.x * 4 + (tl >> 6);
    if (wave >= LIN_WAVES) return;

    const int lane = tl & 63;
    const int n    = wave * 64 + lane;
    const bool act = (n < N_NODES);
    float x0 = 0.f, x1 = 0.f, x2 = 0.f;
    if (act) { x0 = x[n * 3]; x1 = x[n * 3 + 1]; x2 = x[n * 3 + 2]; }

    v16f a0, a1, a2, a3;
#pragma unroll
    for (int i = 0; i < 16; ++i) { a0[i] = 0.f; a1[i] = 0.f; a2[i] = 0.f; a3[i] = 0.f; }

    for (int k = 0; k < 64; ++k) {
        const float w0 = W1[k];                   // wave-uniform -> s_load
        const float w1 = W1[64 + k];
        const float w2 = W1[128 + k];
        const float bb = b1[k];
        const float hk = fmaxf(fmaf(x0, w0, fmaf(x1, w1, fmaf(x2, w2, bb))), 0.f);

        const float4* __restrict__ r4 = (const float4*)(Wg + (size_t)k * 64);
        const float4 p0 = r4[0],  p1 = r4[1],  p2 = r4[2],  p3 = r4[3];
        const float4 p4 = r4[4],  p5 = r4[5],  p6 = r4[6],  p7 = r4[7];
        const float4 p8 = r4[8],  p9 = r4[9],  pa = r4[10], pb = r4[11];
        const float4 pc = r4[12], pd = r4[13], pe = r4[14], pf = r4[15];

        FMA16(a0, p0, p1, p2, p3);
        FMA16(a1, p4, p5, p6, p7);
        FMA16(a2, p8, p9, pa, pb);
        FMA16(a3, pc, pd, pe, pf);
    }

    if (act) {
        uint4* __restrict__ dp = (uint4*)(hb_g + (size_t)n * 64);
        dp[0] = make_uint4(pk2(a0[0],  a0[1]),  pk2(a0[2],  a0[3]),
                           pk2(a0[4],  a0[5]),  pk2(a0[6],  a0[7]));
        dp[1] = make_uint4(pk2(a0[8],  a0[9]),  pk2(a0[10], a0[11]),
                           pk2(a0[12], a0[13]), pk2(a0[14], a0[15]));
        dp[2] = make_uint4(pk2(a1[0],  a1[1]),  pk2(a1[2],  a1[3]),
                           pk2(a1[4],  a1[5]),  pk2(a1[6],  a1[7]));
        dp[3] = make_uint4(pk2(a1[8],  a1[9]),  pk2(a1[10], a1[11]),
                           pk2(a1[12], a1[13]), pk2(a1[14], a1[15]));
        dp[4] = make_uint4(pk2(a2[0],  a2[1]),  pk2(a2[2],  a2[3]),
                           pk2(a2[4],  a2[5]),  pk2(a2[6],  a2[7]));
        dp[5] = make_uint4(pk2(a2[8],  a2[9]),  pk2(a2[10], a2[11]),
                           pk2(a2[12], a2[13]), pk2(a2[14], a2[15]));
        dp[6] = make_uint4(pk2(a3[0],  a3[1]),  pk2(a3[2],  a3[3]),
                           pk2(a3[4],  a3[5]),  pk2(a3[6],  a3[7]));
        dp[7] = make_uint4(pk2(a3[8],  a3[9]),  pk2(a3[10], a3[11]),
                           pk2(a3[12], a3[13]), pk2(a3[14], a3[15]));
    }
}

// ---------------------------------------------------------------------------
// Kernel 3: hb_g[n][c] *= rsqrt(cnt[n]+1)  (in place, dword grain, ~6 us)
// ---------------------------------------------------------------------------
__global__ void scale_kernel(const int* __restrict__ cnt,
                             unsigned int* __restrict__ g2)
{
    const int t = blockIdx.x * blockDim.x + threadIdx.x;
    if (t >= N_NODES * 32) return;
    const int node = t >> 5;
    const float di = rsqrtf((float)(cnt[node] + 1));
    const unsigned int v = g2[t];
    const float lo = bf2f((unsigned short)(v & 0xFFFFu)) * di;
    const float hi = bf2f((unsigned short)(v >> 16)) * di;
    g2[t] = (unsigned int)f2bf(lo) | ((unsigned int)f2bf(hi) << 16);
}

// ---------------------------------------------------------------------------
// Kernel 4: gather + epilogue (R14/R15/R16 form, unchanged).
// ---------------------------------------------------------------------------
__global__ void gather_final_kernel(const unsigned short* __restrict__ hb_g,
                                    const int* __restrict__ cnt,
                                    const int* __restrict__ ell,
                                    const float* __restrict__ x,
                                    const float* __restrict__ W1,
                                    const float* __restrict__ b1,
                                    const float* __restrict__ bg,
                                    const float* __restrict__ gamma,
                                    const float* __restrict__ beta,
                                    float* __restrict__ out)
{
    __shared__ int sell[64 * SCOL];       // 12 KB
    __shared__ int lcnt[64];
    const int tl = threadIdx.x;           // 256 threads = 4 waves
    const int b  = blockIdx.x;
    const int nb = b * 64;

    if (tl < 64) {
        const int n = nb + tl;
        lcnt[tl] = (n < N_NODES) ? cnt[n] : 0;
    }
    {
        const int r = tl >> 2;            // row 0..63
        const int q = tl & 3;             // quad 0..3
        const int nr = nb + r;
        if (nr < N_NODES) {
            const int4* __restrict__ grow = (const int4*)(ell + (size_t)nr * PAD);
            int4* __restrict__ srow = (int4*)(sell + r * SCOL);
            srow[q]     = grow[q];        // cols  0..15
            srow[q + 4] = grow[q + 4];    // cols 16..31
            srow[q + 8] = grow[q + 8];    // cols 32..47
        }
    }
    __syncthreads();

    const int lane = tl & 63;
    const int w    = tl >> 6;
    const float w0 = W1[lane], w1 = W1[64 + lane], w2 = W1[128 + lane];
    const float bb1 = b1[lane];
    const float bgl = bg[lane];
    const float g0 = gamma[lane], g1 = gamma[64 + lane];
    const float be0 = beta[lane], be1 = beta[64 + lane];

    for (int nl = w; nl < 64; nl += 4) {
        const int n = nb + nl;
        if (n >= N_NODES) break;          // only the last block's tail

        const int c    = lcnt[nl];
        const float di = rsqrtf((float)(c + 1));
        const int deg  = (c < PAD) ? c : PAD;
        const int dstg = (deg < SCOL) ? deg : SCOL;
        const int* row = sell + nl * SCOL;

        const float xx0 = x[n * 3], xx1 = x[n * 3 + 1], xx2 = x[n * 3 + 2];
        float acc = bf2f(hb_g[(size_t)n * 64 + lane]);       // self (prescaled)

        int j = 0;
        for (; j + 8 <= dstg; j += 8) {                      // 8 gathers in flight
            const int s0 = row[j + 0], s1 = row[j + 1], s2 = row[j + 2], s3 = row[j + 3];
            const int s4 = row[j + 4], s5 = row[j + 5], s6 = row[j + 6], s7 = row[j + 7];
            const float a0 = bf2f(hb_g[(size_t)s0 * 64 + lane]);
            const float a1 = bf2f(hb_g[(size_t)s1 * 64 + lane]);
            const float a2 = bf2f(hb_g[(size_t)s2 * 64 + lane]);
            const float a3 = bf2f(hb_g[(size_t)s3 * 64 + lane]);
            const float a4 = bf2f(hb_g[(size_t)s4 * 64 + lane]);
            const float a5 = bf2f(hb_g[(size_t)s5 * 64 + lane]);
            const float a6 = bf2f(hb_g[(size_t)s6 * 64 + lane]);
            const float a7 = bf2f(hb_g[(size_t)s7 * 64 + lane]);
            acc += ((a0 + a1) + (a2 + a3)) + ((a4 + a5) + (a6 + a7));
        }
        if (j + 4 <= dstg) {
            const int s0 = row[j + 0], s1 = row[j + 1], s2 = row[j + 2], s3 = row[j + 3];
            acc += (bf2f(hb_g[(size_t)s0 * 64 + lane]) + bf2f(hb_g[(size_t)s1 * 64 + lane]))
                 + (bf2f(hb_g[(size_t)s2 * 64 + lane]) + bf2f(hb_g[(size_t)s3 * 64 + lane]));
            j += 4;
        }
        for (; j < dstg; ++j) acc += bf2f(hb_g[(size_t)row[j] * 64 + lane]);
        // astronomically-rare tail (deg > 48): read global ELL row directly
        for (; j < deg; ++j)
            acc += bf2f(hb_g[(size_t)ell[(size_t)n * PAD + j] * 64 + lane]);

        float h  = fmaxf(fmaf(xx0, w0, fmaf(xx1, w1, fmaf(xx2, w2, bb1))), 0.f);
        float h2 = fmaxf(fmaf(di, acc, bgl), 0.f);

        float sum = h + h2;
#pragma unroll
        for (int o = 32; o > 0; o >>= 1) sum += __shfl_xor(sum, o, 64);
        const float mu = sum * (1.0f / 128.0f);

        const float dA = h  - mu;
        const float dB = h2 - mu;
        float vs = dA * dA + dB * dB;
#pragma unroll
        for (int o = 32; o > 0; o >>= 1) vs += __shfl_xor(vs, o, 64);
        const float rr = rsqrtf(vs * (1.0f / 128.0f) + EPS_);

        out[(size_t)n * 128 + lane]      = dA * rr * g0 + be0;
        out[(size_t)n * 128 + 64 + lane] = dB * rr * g1 + be1;
    }
}

// ---------------------------------------------------------------------------
extern "C" void kernel_launch(void* const* d_in, const int* in_sizes, int n_in,
                              void* d_out, int out_size, void* d_ws, size_t ws_size,
                              hipStream_t stream)
{
    const float* x     = (const float*)d_in[0];
    const int*   edge  = (const int*)  d_in[1];   // [2, E]: row0 = src, row1 = dst
    const float* W1    = (const float*)d_in[2];
    const float* b1    = (const float*)d_in[3];
    const float* Wg    = (const float*)d_in[4];
    const float* bg    = (const float*)d_in[5];
    const float* gamma = (const float*)d_in[6];
    const float* beta  = (const float*)d_in[7];
    float*       out   = (float*)d_out;

    // Workspace (~38.8 MB): hb_g | ell | cnt  (16B-aligned)
    char*  ws  = (char*)d_ws;
    size_t p   = 0;
    unsigned short* hb_g = (unsigned short*)(ws + p); p += (size_t)N_NODES * 64 * sizeof(unsigned short);
    int*            ell  = (int*)           (ws + p); p += (size_t)N_NODES * PAD * sizeof(int);
    int*            cnt  = (int*)           (ws + p);

    const int* src = edge;
    const int* dst = edge + N_EDGES;

    hipMemsetAsync(cnt, 0, (size_t)N_NODES * sizeof(int), stream);

    edge_kernel<<<NB_EDGE, 256, 0, stream>>>(src, dst, cnt, ell);
    lin_kernel <<<NB_LIN,  256, 0, stream>>>(x, W1, b1, Wg, hb_g);
    scale_kernel<<<(N_NODES * 32 + 255) / 256, 256, 0, stream>>>(cnt, (unsigned int*)hb_g);
    gather_final_kernel<<<(N_NODES + 63) / 64, 256, 0, stream>>>(hb_g, cnt, ell,
                                                                 x, W1, b1,
                                                                 bg, gamma, beta, out);
}

// Round 10
// 239.131 us; speedup vs baseline: 1.4370x; 1.0414x over previous
//
#include <hip/hip_runtime.h>
#include <math.h>

#define N_NODES 100000
#define N_EDGES 1600000
#define EPS_    1e-5f
#define PAD     64          // ELL row capacity; P(Poisson(16) > 64) ~ 1e-20
#define SCOL    48          // staged ELL columns; P(deg > 48) ~ 1e-12/node

// R19: collapse 5 dispatches -> 3; eliminate the two unattributed phases.
//  - fused_edge_lin: R16 XCD-partitioned scatter + register-resident v16f lin
//    running in the atomic-latency shadow (R10 pattern, now without scratch).
//    Wg streamed 4xfloat4 at a time -> VGPR ~110, >=4 waves/SIMD.
//  - gather folds dinv via cnt[s] (wave-uniform 4B loads, L2-resident 400KB)
//    -> scale_kernel and its 51MB pass deleted. hb_g stays unscaled.
// R18 attribution: edge 73us (top); lin/scale/gather each <73; sum ~165us.

#define NCHUNK_E 782        // ceil(E/2048)
#define EPB_E    2048
#define NB_EDGE  (NCHUNK_E * 8)      // 6256 blocks; sibling p owns one dst range
#define PART_SZ  12500      // N_NODES / 8

#define LIN_WAVES 1563      // ceil(N/64): one wave = 64 nodes, lane = node

typedef float v16f __attribute__((ext_vector_type(16)));

// ---- bf16 helpers (raw ushort storage, RNE on pack) -----------------------
__device__ __forceinline__ float bf2f(unsigned short u) {
    union { unsigned int i; float f; } v; v.i = (unsigned int)u << 16; return v.f;
}
__device__ __forceinline__ unsigned short f2bf(float f) {
    union { float f; unsigned int i; } v; v.f = f;
    unsigned int b = v.i + 0x7FFFu + ((v.i >> 16) & 1u);   // round-to-nearest-even
    return (unsigned short)(b >> 16);
}
__device__ __forceinline__ unsigned int pk2(float lo, float hi) {
    return (unsigned int)f2bf(lo) | ((unsigned int)f2bf(hi) << 16);
}

#define FMA16(A, wv0, wv1, wv2, wv3)                                          \
    do {                                                                      \
        A[0]  = fmaf(hk, wv0.x, A[0]);  A[1]  = fmaf(hk, wv0.y, A[1]);        \
        A[2]  = fmaf(hk, wv0.z, A[2]);  A[3]  = fmaf(hk, wv0.w, A[3]);        \
        A[4]  = fmaf(hk, wv1.x, A[4]);  A[5]  = fmaf(hk, wv1.y, A[5]);        \
        A[6]  = fmaf(hk, wv1.z, A[6]);  A[7]  = fmaf(hk, wv1.w, A[7]);        \
        A[8]  = fmaf(hk, wv2.x, A[8]);  A[9]  = fmaf(hk, wv2.y, A[9]);        \
        A[10] = fmaf(hk, wv2.z, A[10]); A[11] = fmaf(hk, wv2.w, A[11]);       \
        A[12] = fmaf(hk, wv3.x, A[12]); A[13] = fmaf(hk, wv3.y, A[13]);       \
        A[14] = fmaf(hk, wv3.z, A[14]); A[15] = fmaf(hk, wv3.w, A[15]);       \
    } while (0)

// ---------------------------------------------------------------------------
// Kernel 1: fused edge scatter + lin.
// Phase A-issue: 8 edges/thread (int4 bulk), partition filter, atomics issued.
// Phase B: waves 0..1562 run lin (register acc, streamed Wg) in the shadow.
// Phase A-complete: ELL stores (atomic returns drained under Phase B).
// ---------------------------------------------------------------------------
__global__ void fused_edge_lin_kernel(const int* __restrict__ src,
                                      const int* __restrict__ dst,
                                      const float* __restrict__ x,
                                      const float* __restrict__ W1,
                                      const float* __restrict__ b1,
                                      const float* __restrict__ Wg,
                                      int* __restrict__ cnt,
                                      int* __restrict__ ell,
                                      unsigned short* __restrict__ hb_g)
{
    const int tl    = threadIdx.x;
    const int part  = blockIdx.x & 7;          // aligns with round-robin XCD dispatch
    const int chunk = blockIdx.x >> 3;
    const int lo    = part * PART_SZ;
    const int hi    = lo + PART_SZ;

    // ---- Phase A issue: load 8 edges, claim owned ones -------------------
    const int ebase = chunk * EPB_E + tl * 8;
    int dv[8], sv[8], pos[8];
    if (ebase + 8 <= N_EDGES) {
        const int4 d0 = *(const int4*)(dst + ebase);
        const int4 d1 = *(const int4*)(dst + ebase + 4);
        const int4 s0 = *(const int4*)(src + ebase);
        const int4 s1 = *(const int4*)(src + ebase + 4);
        dv[0] = d0.x; dv[1] = d0.y; dv[2] = d0.z; dv[3] = d0.w;
        dv[4] = d1.x; dv[5] = d1.y; dv[6] = d1.z; dv[7] = d1.w;
        sv[0] = s0.x; sv[1] = s0.y; sv[2] = s0.z; sv[3] = s0.w;
        sv[4] = s1.x; sv[5] = s1.y; sv[6] = s1.z; sv[7] = s1.w;
    } else {
#pragma unroll
        for (int j = 0; j < 8; ++j) {
            const int e = ebase + j;
            if (e < N_EDGES) { dv[j] = dst[e]; sv[j] = src[e]; }
            else             { dv[j] = -1;     sv[j] = 0;      }
        }
    }
#pragma unroll
    for (int j = 0; j < 8; ++j) {
        pos[j] = -1;
        if (dv[j] >= lo && dv[j] < hi) pos[j] = atomicAdd(&cnt[dv[j]], 1);
    }

    // ---- Phase B: lin (waves 0..1562), atomic returns drain underneath ---
    const int wave = blockIdx.x * 4 + (tl >> 6);
    if (wave < LIN_WAVES) {
        const int lane = tl & 63;
        const int n    = wave * 64 + lane;
        const bool act = (n < N_NODES);
        float x0 = 0.f, x1 = 0.f, x2 = 0.f;
        if (act) { x0 = x[n * 3]; x1 = x[n * 3 + 1]; x2 = x[n * 3 + 2]; }

        v16f a0, a1, a2, a3;
#pragma unroll
        for (int i = 0; i < 16; ++i) { a0[i] = 0.f; a1[i] = 0.f; a2[i] = 0.f; a3[i] = 0.f; }

        for (int k = 0; k < 64; ++k) {
            const float w0 = W1[k];               // wave-uniform
            const float w1 = W1[64 + k];
            const float w2 = W1[128 + k];
            const float bb = b1[k];
            const float hk = fmaxf(fmaf(x0, w0, fmaf(x1, w1, fmaf(x2, w2, bb))), 0.f);

            const float4* __restrict__ r4 = (const float4*)(Wg + (size_t)k * 64);
            {
                const float4 p0 = r4[0], p1 = r4[1], p2 = r4[2], p3 = r4[3];
                FMA16(a0, p0, p1, p2, p3);
            }
            {
                const float4 p0 = r4[4], p1 = r4[5], p2 = r4[6], p3 = r4[7];
                FMA16(a1, p0, p1, p2, p3);
            }
            {
                const float4 p0 = r4[8], p1 = r4[9], p2 = r4[10], p3 = r4[11];
                FMA16(a2, p0, p1, p2, p3);
            }
            {
                const float4 p0 = r4[12], p1 = r4[13], p2 = r4[14], p3 = r4[15];
                FMA16(a3, p0, p1, p2, p3);
            }
        }

        if (act) {
            uint4* __restrict__ dp = (uint4*)(hb_g + (size_t)n * 64);
            dp[0] = make_uint4(pk2(a0[0],  a0[1]),  pk2(a0[2],  a0[3]),
                               pk2(a0[4],  a0[5]),  pk2(a0[6],  a0[7]));
            dp[1] = make_uint4(pk2(a0[8],  a0[9]),  pk2(a0[10], a0[11]),
                               pk2(a0[12], a0[13]), pk2(a0[14], a0[15]));
            dp[2] = make_uint4(pk2(a1[0],  a1[1]),  pk2(a1[2],  a1[3]),
                               pk2(a1[4],  a1[5]),  pk2(a1[6],  a1[7]));
            dp[3] = make_uint4(pk2(a1[8],  a1[9]),  pk2(a1[10], a1[11]),
                               pk2(a1[12], a1[13]), pk2(a1[14], a1[15]));
            dp[4] = make_uint4(pk2(a2[0],  a2[1]),  pk2(a2[2],  a2[3]),
                               pk2(a2[4],  a2[5]),  pk2(a2[6],  a2[7]));
            dp[5] = make_uint4(pk2(a2[8],  a2[9]),  pk2(a2[10], a2[11]),
                               pk2(a2[12], a2[13]), pk2(a2[14], a2[15]));
            dp[6] = make_uint4(pk2(a3[0],  a3[1]),  pk2(a3[2],  a3[3]),
                               pk2(a3[4],  a3[5]),  pk2(a3[6],  a3[7]));
            dp[7] = make_uint4(pk2(a3[8],  a3[9]),  pk2(a3[10], a3[11]),
                               pk2(a3[12], a3[13]), pk2(a3[14], a3[15]));
        }
    }

    // ---- Phase A complete: scattered ELL stores --------------------------
#pragma unroll
    for (int j = 0; j < 8; ++j)
        if (pos[j] >= 0 && pos[j] < PAD) ell[dv[j] * PAD + pos[j]] = sv[j];
}

// ---------------------------------------------------------------------------
// Kernel 2: gather + epilogue, dinv folded from cnt (scale pass deleted).
//   acc = dinv[n]*hg[n] + sum_j dinv[s_j]*hg[s_j]   (dinv = rsqrt(cnt+1))
//   h2  = relu(dinv[n]*acc + bg);  h = relu(x.W1+b1)
//   out = LayerNorm128([h,h2])*gamma + beta
// ---------------------------------------------------------------------------
__global__ void gather_final_kernel(const unsigned short* __restrict__ hb_g,
                                    const int* __restrict__ cnt,
                                    const int* __restrict__ ell,
                                    const float* __restrict__ x,
                                    const float* __restrict__ W1,
                                    const float* __restrict__ b1,
                                    const float* __restrict__ bg,
                                    const float* __restrict__ gamma,
                                    const float* __restrict__ beta,
                                    float* __restrict__ out)
{
    __shared__ int sell[64 * SCOL];       // 12 KB
    __shared__ int lcnt[64];
    const int tl = threadIdx.x;           // 256 threads = 4 waves
    const int b  = blockIdx.x;
    const int nb = b * 64;

    if (tl < 64) {
        const int n = nb + tl;
        lcnt[tl] = (n < N_NODES) ? cnt[n] : 0;
    }
    {
        const int r = tl >> 2;            // row 0..63
        const int q = tl & 3;             // quad 0..3
        const int nr = nb + r;
        if (nr < N_NODES) {
            const int4* __restrict__ grow = (const int4*)(ell + (size_t)nr * PAD);
            int4* __restrict__ srow = (int4*)(sell + r * SCOL);
            srow[q]     = grow[q];        // cols  0..15
            srow[q + 4] = grow[q + 4];    // cols 16..31
            srow[q + 8] = grow[q + 8];    // cols 32..47
        }
    }
    __syncthreads();

    const int lane = tl & 63;
    const int w    = tl >> 6;
    const float w0 = W1[lane], w1 = W1[64 + lane], w2 = W1[128 + lane];
    const float bb1 = b1[lane];
    const float bgl = bg[lane];
    const float g0 = gamma[lane], g1 = gamma[64 + lane];
    const float be0 = beta[lane], be1 = beta[64 + lane];

    for (int nl = w; nl < 64; nl += 4) {
        const int n = nb + nl;
        if (n >= N_NODES) break;          // only the last block's tail

        const int c    = lcnt[nl];
        const float di = rsqrtf((float)(c + 1));
        const int deg  = (c < PAD) ? c : PAD;
        const int dstg = (deg < SCOL) ? deg : SCOL;
        const int* row = sell + nl * SCOL;

        const float xx0 = x[n * 3], xx1 = x[n * 3 + 1], xx2 = x[n * 3 + 2];
        float acc = di * bf2f(hb_g[(size_t)n * 64 + lane]);  // self loop

        int j = 0;
        for (; j + 8 <= dstg; j += 8) {                      // 8 gathers in flight
            const int s0 = row[j + 0], s1 = row[j + 1], s2 = row[j + 2], s3 = row[j + 3];
            const int s4 = row[j + 4], s5 = row[j + 5], s6 = row[j + 6], s7 = row[j + 7];
            const float a0 = bf2f(hb_g[(size_t)s0 * 64 + lane]);
            const float a1 = bf2f(hb_g[(size_t)s1 * 64 + lane]);
            const float a2 = bf2f(hb_g[(size_t)s2 * 64 + lane]);
            const float a3 = bf2f(hb_g[(size_t)s3 * 64 + lane]);
            const float a4 = bf2f(hb_g[(size_t)s4 * 64 + lane]);
            const float a5 = bf2f(hb_g[(size_t)s5 * 64 + lane]);
            const float a6 = bf2f(hb_g[(size_t)s6 * 64 + lane]);
            const float a7 = bf2f(hb_g[(size_t)s7 * 64 + lane]);
            const float v0 = rsqrtf((float)(cnt[s0] + 1));
            const float v1 = rsqrtf((float)(cnt[s1] + 1));
            const float v2 = rsqrtf((float)(cnt[s2] + 1));
            const float v3 = rsqrtf((float)(cnt[s3] + 1));
            const float v4 = rsqrtf((float)(cnt[s4] + 1));
            const float v5 = rsqrtf((float)(cnt[s5] + 1));
            const float v6 = rsqrtf((float)(cnt[s6] + 1));
            const float v7 = rsqrtf((float)(cnt[s7] + 1));
            acc = fmaf(v0, a0, acc); acc = fmaf(v1, a1, acc);
            acc = fmaf(v2, a2, acc); acc = fmaf(v3, a3, acc);
            acc = fmaf(v4, a4, acc); acc = fmaf(v5, a5, acc);
            acc = fmaf(v6, a6, acc); acc = fmaf(v7, a7, acc);
        }
        for (; j < dstg; ++j) {
            const int s = row[j];
            acc = fmaf(rsqrtf((float)(cnt[s] + 1)),
                       bf2f(hb_g[(size_t)s * 64 + lane]), acc);
        }
        // astronomically-rare tail (deg > 48): read global ELL row directly
        for (; j < deg; ++j) {
            const int s = ell[(size_t)n * PAD + j];
            acc = fmaf(rsqrtf((float)(cnt[s] + 1)),
                       bf2f(hb_g[(size_t)s * 64 + lane]), acc);
        }

        float h  = fmaxf(fmaf(xx0, w0, fmaf(xx1, w1, fmaf(xx2, w2, bb1))), 0.f);
        float h2 = fmaxf(fmaf(di, acc, bgl), 0.f);

        float sum = h + h2;
#pragma unroll
        for (int o = 32; o > 0; o >>= 1) sum += __shfl_xor(sum, o, 64);
        const float mu = sum * (1.0f / 128.0f);

        const float dA = h  - mu;
        const float dB = h2 - mu;
        float vs = dA * dA + dB * dB;
#pragma unroll
        for (int o = 32; o > 0; o >>= 1) vs += __shfl_xor(vs, o, 64);
        const float rr = rsqrtf(vs * (1.0f / 128.0f) + EPS_);

        out[(size_t)n * 128 + lane]      = dA * rr * g0 + be0;
        out[(size_t)n * 128 + 64 + lane] = dB * rr * g1 + be1;
    }
}

// ---------------------------------------------------------------------------
extern "C" void kernel_launch(void* const* d_in, const int* in_sizes, int n_in,
                              void* d_out, int out_size, void* d_ws, size_t ws_size,
                              hipStream_t stream)
{
    const float* x     = (const float*)d_in[0];
    const int*   edge  = (const int*)  d_in[1];   // [2, E]: row0 = src, row1 = dst
    const float* W1    = (const float*)d_in[2];
    const float* b1    = (const float*)d_in[3];
    const float* Wg    = (const float*)d_in[4];
    const float* bg    = (const float*)d_in[5];
    const float* gamma = (const float*)d_in[6];
    const float* beta  = (const float*)d_in[7];
    float*       out   = (float*)d_out;

    // Workspace (~38.8 MB): hb_g | ell | cnt  (16B-aligned)
    char*  ws  = (char*)d_ws;
    size_t p   = 0;
    unsigned short* hb_g = (unsigned short*)(ws + p); p += (size_t)N_NODES * 64 * sizeof(unsigned short);
    int*            ell  = (int*)           (ws + p); p += (size_t)N_NODES * PAD * sizeof(int);
    int*            cnt  = (int*)           (ws + p);

    const int* src = edge;
    const int* dst = edge + N_EDGES;

    hipMemsetAsync(cnt, 0, (size_t)N_NODES * sizeof(int), stream);

    fused_edge_lin_kernel<<<NB_EDGE, 256, 0, stream>>>(src, dst, x, W1, b1, Wg,
                                                       cnt, ell, hb_g);
    gather_final_kernel<<<(N_NODES + 63) / 64, 256, 0, stream>>>(hb_g, cnt, ell,
                                                                 x, W1, b1,
                                                                 bg, gamma, beta, out);
}

// Round 11
// 215.167 us; speedup vs baseline: 1.5971x; 1.1114x over previous
//
#include <hip/hip_runtime.h>
#include <math.h>

#define N_NODES 100000
#define N_EDGES 1600000
#define EPS_    1e-5f
#define PAD     64          // ELL row capacity; P(Poisson(16) > 64) ~ 1e-20
#define SCOL    48          // staged ELL columns; P(deg > 48) ~ 1e-12/node

// R20: revert gather to PRESCALED hb_g. R19's per-edge dinv fold made gather
// VALU-issue-bound (64% VALUBusy, 92us): +4 wave-inst/edge (cnt load, cvt,
// rsqrt, fma) x 1.6M edges ~= the whole 73->92 regression vs R17's prescaled
// form (<73us). Restore scale_kernel (25.6MB sequential, ~6-10us) and strip
// the per-edge math to lshl+fma. Gather also reads LDS rows as int4 (2x
// ds_read_b128 per 8-edge batch, was 8x b32). fused_edge_lin byte-identical
// to R19 -> with gather ~70, fused becomes top dispatch = first direct
// counters for it next round.

#define NCHUNK_E 782        // ceil(E/2048)
#define EPB_E    2048
#define NB_EDGE  (NCHUNK_E * 8)      // 6256 blocks; sibling p owns one dst range
#define PART_SZ  12500      // N_NODES / 8

#define LIN_WAVES 1563      // ceil(N/64): one wave = 64 nodes, lane = node

typedef float v16f __attribute__((ext_vector_type(16)));

// ---- bf16 helpers (raw ushort storage, RNE on pack) -----------------------
__device__ __forceinline__ float bf2f(unsigned short u) {
    union { unsigned int i; float f; } v; v.i = (unsigned int)u << 16; return v.f;
}
__device__ __forceinline__ unsigned short f2bf(float f) {
    union { float f; unsigned int i; } v; v.f = f;
    unsigned int b = v.i + 0x7FFFu + ((v.i >> 16) & 1u);   // round-to-nearest-even
    return (unsigned short)(b >> 16);
}
__device__ __forceinline__ unsigned int pk2(float lo, float hi) {
    return (unsigned int)f2bf(lo) | ((unsigned int)f2bf(hi) << 16);
}

#define FMA16(A, wv0, wv1, wv2, wv3)                                          \
    do {                                                                      \
        A[0]  = fmaf(hk, wv0.x, A[0]);  A[1]  = fmaf(hk, wv0.y, A[1]);        \
        A[2]  = fmaf(hk, wv0.z, A[2]);  A[3]  = fmaf(hk, wv0.w, A[3]);        \
        A[4]  = fmaf(hk, wv1.x, A[4]);  A[5]  = fmaf(hk, wv1.y, A[5]);        \
        A[6]  = fmaf(hk, wv1.z, A[6]);  A[7]  = fmaf(hk, wv1.w, A[7]);        \
        A[8]  = fmaf(hk, wv2.x, A[8]);  A[9]  = fmaf(hk, wv2.y, A[9]);        \
        A[10] = fmaf(hk, wv2.z, A[10]); A[11] = fmaf(hk, wv2.w, A[11]);       \
        A[12] = fmaf(hk, wv3.x, A[12]); A[13] = fmaf(hk, wv3.y, A[13]);       \
        A[14] = fmaf(hk, wv3.z, A[14]); A[15] = fmaf(hk, wv3.w, A[15]);       \
    } while (0)

// ---------------------------------------------------------------------------
// Kernel 1: fused edge scatter + lin (R19 form, unchanged).
// ---------------------------------------------------------------------------
__global__ void fused_edge_lin_kernel(const int* __restrict__ src,
                                      const int* __restrict__ dst,
                                      const float* __restrict__ x,
                                      const float* __restrict__ W1,
                                      const float* __restrict__ b1,
                                      const float* __restrict__ Wg,
                                      int* __restrict__ cnt,
                                      int* __restrict__ ell,
                                      unsigned short* __restrict__ hb_g)
{
    const int tl    = threadIdx.x;
    const int part  = blockIdx.x & 7;          // aligns with round-robin XCD dispatch
    const int chunk = blockIdx.x >> 3;
    const int lo    = part * PART_SZ;
    const int hi    = lo + PART_SZ;

    // ---- Phase A issue: load 8 edges, claim owned ones -------------------
    const int ebase = chunk * EPB_E + tl * 8;
    int dv[8], sv[8], pos[8];
    if (ebase + 8 <= N_EDGES) {
        const int4 d0 = *(const int4*)(dst + ebase);
        const int4 d1 = *(const int4*)(dst + ebase + 4);
        const int4 s0 = *(const int4*)(src + ebase);
        const int4 s1 = *(const int4*)(src + ebase + 4);
        dv[0] = d0.x; dv[1] = d0.y; dv[2] = d0.z; dv[3] = d0.w;
        dv[4] = d1.x; dv[5] = d1.y; dv[6] = d1.z; dv[7] = d1.w;
        sv[0] = s0.x; sv[1] = s0.y; sv[2] = s0.z; sv[3] = s0.w;
        sv[4] = s1.x; sv[5] = s1.y; sv[6] = s1.z; sv[7] = s1.w;
    } else {
#pragma unroll
        for (int j = 0; j < 8; ++j) {
            const int e = ebase + j;
            if (e < N_EDGES) { dv[j] = dst[e]; sv[j] = src[e]; }
            else             { dv[j] = -1;     sv[j] = 0;      }
        }
    }
#pragma unroll
    for (int j = 0; j < 8; ++j) {
        pos[j] = -1;
        if (dv[j] >= lo && dv[j] < hi) pos[j] = atomicAdd(&cnt[dv[j]], 1);
    }

    // ---- Phase B: lin (waves 0..1562), atomic returns drain underneath ---
    const int wave = blockIdx.x * 4 + (tl >> 6);
    if (wave < LIN_WAVES) {
        const int lane = tl & 63;
        const int n    = wave * 64 + lane;
        const bool act = (n < N_NODES);
        float x0 = 0.f, x1 = 0.f, x2 = 0.f;
        if (act) { x0 = x[n * 3]; x1 = x[n * 3 + 1]; x2 = x[n * 3 + 2]; }

        v16f a0, a1, a2, a3;
#pragma unroll
        for (int i = 0; i < 16; ++i) { a0[i] = 0.f; a1[i] = 0.f; a2[i] = 0.f; a3[i] = 0.f; }

        for (int k = 0; k < 64; ++k) {
            const float w0 = W1[k];               // wave-uniform
            const float w1 = W1[64 + k];
            const float w2 = W1[128 + k];
            const float bb = b1[k];
            const float hk = fmaxf(fmaf(x0, w0, fmaf(x1, w1, fmaf(x2, w2, bb))), 0.f);

            const float4* __restrict__ r4 = (const float4*)(Wg + (size_t)k * 64);
            {
                const float4 p0 = r4[0], p1 = r4[1], p2 = r4[2], p3 = r4[3];
                FMA16(a0, p0, p1, p2, p3);
            }
            {
                const float4 p0 = r4[4], p1 = r4[5], p2 = r4[6], p3 = r4[7];
                FMA16(a1, p0, p1, p2, p3);
            }
            {
                const float4 p0 = r4[8], p1 = r4[9], p2 = r4[10], p3 = r4[11];
                FMA16(a2, p0, p1, p2, p3);
            }
            {
                const float4 p0 = r4[12], p1 = r4[13], p2 = r4[14], p3 = r4[15];
                FMA16(a3, p0, p1, p2, p3);
            }
        }

        if (act) {
            uint4* __restrict__ dp = (uint4*)(hb_g + (size_t)n * 64);
            dp[0] = make_uint4(pk2(a0[0],  a0[1]),  pk2(a0[2],  a0[3]),
                               pk2(a0[4],  a0[5]),  pk2(a0[6],  a0[7]));
            dp[1] = make_uint4(pk2(a0[8],  a0[9]),  pk2(a0[10], a0[11]),
                               pk2(a0[12], a0[13]), pk2(a0[14], a0[15]));
            dp[2] = make_uint4(pk2(a1[0],  a1[1]),  pk2(a1[2],  a1[3]),
                               pk2(a1[4],  a1[5]),  pk2(a1[6],  a1[7]));
            dp[3] = make_uint4(pk2(a1[8],  a1[9]),  pk2(a1[10], a1[11]),
                               pk2(a1[12], a1[13]), pk2(a1[14], a1[15]));
            dp[4] = make_uint4(pk2(a2[0],  a2[1]),  pk2(a2[2],  a2[3]),
                               pk2(a2[4],  a2[5]),  pk2(a2[6],  a2[7]));
            dp[5] = make_uint4(pk2(a2[8],  a2[9]),  pk2(a2[10], a2[11]),
                               pk2(a2[12], a2[13]), pk2(a2[14], a2[15]));
            dp[6] = make_uint4(pk2(a3[0],  a3[1]),  pk2(a3[2],  a3[3]),
                               pk2(a3[4],  a3[5]),  pk2(a3[6],  a3[7]));
            dp[7] = make_uint4(pk2(a3[8],  a3[9]),  pk2(a3[10], a3[11]),
                               pk2(a3[12], a3[13]), pk2(a3[14], a3[15]));
        }
    }

    // ---- Phase A complete: scattered ELL stores --------------------------
#pragma unroll
    for (int j = 0; j < 8; ++j)
        if (pos[j] >= 0 && pos[j] < PAD) ell[dv[j] * PAD + pos[j]] = sv[j];
}

// ---------------------------------------------------------------------------
// Kernel 2: hb_g[n][c] *= rsqrt(cnt[n]+1)  (in place, dword grain, ~6-10 us)
// ---------------------------------------------------------------------------
__global__ void scale_kernel(const int* __restrict__ cnt,
                             unsigned int* __restrict__ g2)
{
    const int t = blockIdx.x * blockDim.x + threadIdx.x;
    if (t >= N_NODES * 32) return;
    const int node = t >> 5;
    const float di = rsqrtf((float)(cnt[node] + 1));
    const unsigned int v = g2[t];
    const float lo = bf2f((unsigned short)(v & 0xFFFFu)) * di;
    const float hi = bf2f((unsigned short)(v >> 16)) * di;
    g2[t] = (unsigned int)f2bf(lo) | ((unsigned int)f2bf(hi) << 16);
}

// ---------------------------------------------------------------------------
// Kernel 3: gather + epilogue, PRESCALED hb_g (per-edge VALU = lshl+fma).
// 256 threads = 4 waves, 64 nodes per block; coalesced ELL->LDS stage;
// LDS neighbor rows read as int4 (2x ds_read_b128 per 8-edge batch).
// ---------------------------------------------------------------------------
__global__ void gather_final_kernel(const unsigned short* __restrict__ hb_g,
                                    const int* __restrict__ cnt,
                                    const int* __restrict__ ell,
                                    const float* __restrict__ x,
                                    const float* __restrict__ W1,
                                    const float* __restrict__ b1,
                                    const float* __restrict__ bg,
                                    const float* __restrict__ gamma,
                                    const float* __restrict__ beta,
                                    float* __restrict__ out)
{
    __shared__ int sell[64 * SCOL];       // 12 KB
    __shared__ int lcnt[64];
    const int tl = threadIdx.x;           // 256 threads = 4 waves
    const int b  = blockIdx.x;
    const int nb = b * 64;

    if (tl < 64) {
        const int n = nb + tl;
        lcnt[tl] = (n < N_NODES) ? cnt[n] : 0;
    }
    {
        const int r = tl >> 2;            // row 0..63
        const int q = tl & 3;             // quad 0..3
        const int nr = nb + r;
        if (nr < N_NODES) {
            const int4* __restrict__ grow = (const int4*)(ell + (size_t)nr * PAD);
            int4* __restrict__ srow = (int4*)(sell + r * SCOL);
            srow[q]     = grow[q];        // cols  0..15
            srow[q + 4] = grow[q + 4];    // cols 16..31
            srow[q + 8] = grow[q + 8];    // cols 32..47
        }
    }
    __syncthreads();

    const int lane = tl & 63;
    const int w    = tl >> 6;
    const float w0 = W1[lane], w1 = W1[64 + lane], w2 = W1[128 + lane];
    const float bb1 = b1[lane];
    const float bgl = bg[lane];
    const float g0 = gamma[lane], g1 = gamma[64 + lane];
    const float be0 = beta[lane], be1 = beta[64 + lane];

    for (int nl = w; nl < 64; nl += 4) {
        const int n = nb + nl;
        if (n >= N_NODES) break;          // only the last block's tail

        const int c    = lcnt[nl];
        const float di = rsqrtf((float)(c + 1));
        const int deg  = (c < PAD) ? c : PAD;
        const int dstg = (deg < SCOL) ? deg : SCOL;
        const int* row = sell + nl * SCOL;

        const float xx0 = x[n * 3], xx1 = x[n * 3 + 1], xx2 = x[n * 3 + 2];
        float acc = bf2f(hb_g[(size_t)n * 64 + lane]);       // self (prescaled)

        int j = 0;
        for (; j + 8 <= dstg; j += 8) {                      // 8 gathers in flight
            const int4 r0 = *(const int4*)(row + j);
            const int4 r1 = *(const int4*)(row + j + 4);
            const float a0 = bf2f(hb_g[(size_t)r0.x * 64 + lane]);
            const float a1 = bf2f(hb_g[(size_t)r0.y * 64 + lane]);
            const float a2 = bf2f(hb_g[(size_t)r0.z * 64 + lane]);
            const float a3 = bf2f(hb_g[(size_t)r0.w * 64 + lane]);
            const float a4 = bf2f(hb_g[(size_t)r1.x * 64 + lane]);
            const float a5 = bf2f(hb_g[(size_t)r1.y * 64 + lane]);
            const float a6 = bf2f(hb_g[(size_t)r1.z * 64 + lane]);
            const float a7 = bf2f(hb_g[(size_t)r1.w * 64 + lane]);
            acc += ((a0 + a1) + (a2 + a3)) + ((a4 + a5) + (a6 + a7));
        }
        if (j + 4 <= dstg) {
            const int4 r0 = *(const int4*)(row + j);
            acc += (bf2f(hb_g[(size_t)r0.x * 64 + lane]) + bf2f(hb_g[(size_t)r0.y * 64 + lane]))
                 + (bf2f(hb_g[(size_t)r0.z * 64 + lane]) + bf2f(hb_g[(size_t)r0.w * 64 + lane]));
            j += 4;
        }
        for (; j < dstg; ++j) acc += bf2f(hb_g[(size_t)row[j] * 64 + lane]);
        // astronomically-rare tail (deg > 48): read global ELL row directly
        for (; j < deg; ++j)
            acc += bf2f(hb_g[(size_t)ell[(size_t)n * PAD + j] * 64 + lane]);

        float h  = fmaxf(fmaf(xx0, w0, fmaf(xx1, w1, fmaf(xx2, w2, bb1))), 0.f);
        float h2 = fmaxf(fmaf(di, acc, bgl), 0.f);

        float sum = h + h2;
#pragma unroll
        for (int o = 32; o > 0; o >>= 1) sum += __shfl_xor(sum, o, 64);
        const float mu = sum * (1.0f / 128.0f);

        const float dA = h  - mu;
        const float dB = h2 - mu;
        float vs = dA * dA + dB * dB;
#pragma unroll
        for (int o = 32; o > 0; o >>= 1) vs += __shfl_xor(vs, o, 64);
        const float rr = rsqrtf(vs * (1.0f / 128.0f) + EPS_);

        out[(size_t)n * 128 + lane]      = dA * rr * g0 + be0;
        out[(size_t)n * 128 + 64 + lane] = dB * rr * g1 + be1;
    }
}

// ---------------------------------------------------------------------------
extern "C" void kernel_launch(void* const* d_in, const int* in_sizes, int n_in,
                              void* d_out, int out_size, void* d_ws, size_t ws_size,
                              hipStream_t stream)
{
    const float* x     = (const float*)d_in[0];
    const int*   edge  = (const int*)  d_in[1];   // [2, E]: row0 = src, row1 = dst
    const float* W1    = (const float*)d_in[2];
    const float* b1    = (const float*)d_in[3];
    const float* Wg    = (const float*)d_in[4];
    const float* bg    = (const float*)d_in[5];
    const float* gamma = (const float*)d_in[6];
    const float* beta  = (const float*)d_in[7];
    float*       out   = (float*)d_out;

    // Workspace (~38.8 MB): hb_g | ell | cnt  (16B-aligned)
    char*  ws  = (char*)d_ws;
    size_t p   = 0;
    unsigned short* hb_g = (unsigned short*)(ws + p); p += (size_t)N_NODES * 64 * sizeof(unsigned short);
    int*            ell  = (int*)           (ws + p); p += (size_t)N_NODES * PAD * sizeof(int);
    int*            cnt  = (int*)           (ws + p);

    const int* src = edge;
    const int* dst = edge + N_EDGES;

    hipMemsetAsync(cnt, 0, (size_t)N_NODES * sizeof(int), stream);

    fused_edge_lin_kernel<<<NB_EDGE, 256, 0, stream>>>(src, dst, x, W1, b1, Wg,
                                                       cnt, ell, hb_g);
    scale_kernel<<<(N_NODES * 32 + 255) / 256, 256, 0, stream>>>(cnt, (unsigned int*)hb_g);
    gather_final_kernel<<<(N_NODES + 63) / 64, 256, 0, stream>>>(hb_g, cnt, ell,
                                                                 x, W1, b1,
                                                                 bg, gamma, beta, out);
}